// Round 4
// baseline (57.086 us; speedup 1.0000x reference)
//
#include <hip/hip_runtime.h>

// Problem constants (B,N,M,D fixed by setup_inputs: 4, 4096, 1024, 3)
#define BB 4
#define NN 4096
#define MM 1024
#define TN 128             // n-tile
#define TM 128             // m-tile
#define CN (NN / TN)       // 32 n-tiles
#define CM (MM / TM)       // 8 m-tiles
#define FLT_BIG 3.402823466e38f
#define INF_BITS 0x7F800000u

// ---------------------------------------------------------------------------
// Math note: the reference's einsum 'bnik,bnjk->bnij' over diffs (B,N,10,3)
// builds a 10x10 Gram matrix of rank <= 3, so ev[...,0] (smallest of 10
// ascending eigenvalues) is exactly 0 => curvature == 0 => smoothed == 0.
// Only the chamfer loss (output 0) carries real values.
//
// Workspace layout (we use ~340 KB of the ~256 MB ws):
//   pk1    : B*NN float4 (x,y,z,|p|^2) packed points1
//   pk2    : B*MM float4
//   minN   : B*NN uint  — final per-(b,n) min bits (atomicMin-merged)
//   minM   : B*MM uint  — final per-(b,m) min bits
//   ticket : BB uint    — per-batch completion counters
// prep re-initializes ALL of this every call (no reliance on poison state).
// ---------------------------------------------------------------------------

__global__ __launch_bounds__(256) void prep(const float* __restrict__ p1,
                                            const float* __restrict__ p2,
                                            float4* __restrict__ pk1,
                                            float4* __restrict__ pk2,
                                            unsigned int* __restrict__ minN,
                                            unsigned int* __restrict__ minM,
                                            unsigned int* __restrict__ ticket,
                                            float* __restrict__ out,
                                            int out_total) {
    const int i = blockIdx.x * 256 + threadIdx.x;
    if (i < BB * NN) {
        const float x = p1[3 * i], y = p1[3 * i + 1], z = p1[3 * i + 2];
        pk1[i] = make_float4(x, y, z, x * x + y * y + z * z);
        minN[i] = INF_BITS;
    }
    if (i < BB * MM) {
        const float x = p2[3 * i], y = p2[3 * i + 1], z = p2[3 * i + 2];
        pk2[i] = make_float4(x, y, z, x * x + y * y + z * z);
        minM[i] = INF_BITS;
    }
    if (i < out_total) out[i] = 0.0f;
    if (i < BB) ticket[i] = 0;
}

// Fused tile + tail kernel. Block (cn,cm,b) covers a 128x128 (n,m) tile,
// merges its mins into the global per-point min arrays via uint atomicMin
// (valid ordering: values clamped >= 0), then the last-finishing block of
// each batch sums that batch's mins and writes out[b] (single writer).
__global__ __launch_bounds__(128) void chamfer_main(const float4* __restrict__ pk1,
                                                    const float4* __restrict__ pk2,
                                                    unsigned int* __restrict__ minN,
                                                    unsigned int* __restrict__ minM,
                                                    unsigned int* __restrict__ ticket,
                                                    float* __restrict__ out) {
    const int cn = blockIdx.x, cm = blockIdx.y, b = blockIdx.z;
    const int t = threadIdx.x;

    const float4 a  = pk1[(size_t)b * NN + (size_t)cn * TN + t];  // own n-point
    const float4 bp = pk2[(size_t)b * MM + (size_t)cm * TM + t];  // own m-point
    const float4* __restrict__ oN = pk2 + (size_t)b * MM + (size_t)cm * TM;  // uniform
    const float4* __restrict__ oM = pk1 + (size_t)b * NN + (size_t)cn * TN;  // uniform

    float mN0 = FLT_BIG, mN1 = FLT_BIG, mM0 = FLT_BIG, mM1 = FLT_BIG;
    #pragma unroll 8
    for (int i = 0; i < TN; i += 2) {
        const float4 u0 = oN[i], u1 = oN[i + 1];
        const float4 v0 = oM[i], v1 = oM[i + 1];
        mN0 = fminf(mN0, (a.w + u0.w) - 2.0f * (a.x * u0.x + a.y * u0.y + a.z * u0.z));
        mN1 = fminf(mN1, (a.w + u1.w) - 2.0f * (a.x * u1.x + a.y * u1.y + a.z * u1.z));
        mM0 = fminf(mM0, (bp.w + v0.w) - 2.0f * (bp.x * v0.x + bp.y * v0.y + bp.z * v0.z));
        mM1 = fminf(mM1, (bp.w + v1.w) - 2.0f * (bp.x * v1.x + bp.y * v1.y + bp.z * v1.z));
    }
    // clamp: min(max(d2,0)) == max(min(d2),0); >=0 makes uint-bit atomicMin valid
    const float vN = fmaxf(fminf(mN0, mN1), 0.0f);
    const float vM = fmaxf(fminf(mM0, mM1), 0.0f);
    atomicMin(&minN[(size_t)b * NN + (size_t)cn * TN + t], __float_as_uint(vN));
    atomicMin(&minM[(size_t)b * MM + (size_t)cm * TM + t], __float_as_uint(vM));

    // --- tail: last block of this batch reduces the 5120 mins -> out[b] ---
    __threadfence();
    __syncthreads();
    __shared__ unsigned int s_old;
    if (t == 0) s_old = atomicAdd(&ticket[b], 1u);
    __syncthreads();
    if (s_old != (unsigned)(CN * CM - 1)) return;  // not last

    // All other blocks' atomicMins are ordered before their ticket increments
    // (threadfence), so the mins are complete. Volatile loads bypass L1.
    const volatile unsigned int* vN_ = minN + (size_t)b * NN;
    const volatile unsigned int* vM_ = minM + (size_t)b * MM;
    float s = 0.0f;
    for (int i = t; i < NN; i += 128) s += __uint_as_float(vN_[i]);
    for (int i = t; i < MM; i += 128) s += __uint_as_float(vM_[i]);

    __shared__ float red[2];
    const int lane = t & 63, wv = t >> 6;
    #pragma unroll
    for (int off = 32; off > 0; off >>= 1) s += __shfl_down(s, off, 64);
    if (lane == 0) red[wv] = s;
    __syncthreads();
    if (t == 0) out[b] = red[0] + red[1];
}

extern "C" void kernel_launch(void* const* d_in, const int* in_sizes, int n_in,
                              void* d_out, int out_size, void* d_ws, size_t ws_size,
                              hipStream_t stream) {
    const float* p1 = (const float*)d_in[0];  // (B,N,3) fp32
    const float* p2 = (const float*)d_in[1];  // (B,M,3) fp32
    float* out = (float*)d_out;               // [0..3]=total_loss, [4..]=smoothed

    float4* pk1 = (float4*)d_ws;                               // B*NN float4
    float4* pk2 = pk1 + (size_t)BB * NN;                       // B*MM float4
    unsigned int* minN = (unsigned int*)(pk2 + (size_t)BB * MM);  // B*NN uint
    unsigned int* minM = minN + (size_t)BB * NN;                  // B*MM uint
    unsigned int* ticket = minM + (size_t)BB * MM;                // BB uint

    const int total = out_size;  // 4 + B*N = 16388
    hipLaunchKernelGGL(prep, dim3((total + 255) / 256), dim3(256), 0, stream,
                       p1, p2, pk1, pk2, minN, minM, ticket, out, total);
    hipLaunchKernelGGL(chamfer_main, dim3(CN, CM, BB), dim3(TN), 0, stream,
                       pk1, pk2, minN, minM, ticket, out);
}

// Round 5
// 15.214 us; speedup vs baseline: 3.7521x; 3.7521x over previous
//
#include <hip/hip_runtime.h>

// Problem constants (B,N,M,D fixed by setup_inputs: 4, 4096, 1024, 3)
#define BB 4
#define NN 4096
#define MM 1024
#define TN 128             // n-tile
#define TM 128             // m-tile
#define CN (NN / TN)       // 32 n-tiles
#define CM (MM / TM)       // 8 m-tiles
#define FLT_BIG 3.402823466e38f

// ---------------------------------------------------------------------------
// Math note: the reference's einsum 'bnik,bnjk->bnij' over diffs (B,N,10,3)
// builds a 10x10 Gram matrix of rank <= 3, so ev[...,0] (smallest of 10
// ascending eigenvalues) is exactly 0 => curvature == 0 => smoothed == 0.
// Only the chamfer loss (output 0) carries real values.
//
// Round-4 lesson (measured): in-kernel cross-block handoff needs a device
// -scope fence -> L2 writeback per block on non-coherent XCD L2s -> +45us.
// Cross-KERNEL visibility is free (CP end-of-dispatch release). So the
// reduction stays a second kernel.
//
// Workspace (1 MB of ws): wsN[b][cm][n], wsM[b][cn][m] — partial mins,
// every slot written exactly once -> no atomics, no init pass.
// ---------------------------------------------------------------------------

__device__ __forceinline__ float block_reduce_sum_256(float v) {
    __shared__ float red[4];
    const int lane = threadIdx.x & 63;
    const int wv   = threadIdx.x >> 6;
    #pragma unroll
    for (int off = 32; off > 0; off >>= 1) v += __shfl_down(v, off, 64);
    if (lane == 0) red[wv] = v;
    __syncthreads();
    float r = 0.0f;
    if (threadIdx.x == 0) r = red[0] + red[1] + red[2] + red[3];
    return r;  // valid in thread 0 only
}

// K1: fused 128x128 (n,m) tile, both chamfer directions, reading RAW points.
// Difference form (a-u)·(a-u) needs no precomputed norms -> no prep kernel.
// Partner addresses are wave-uniform -> scalar-cache s_load broadcasts.
// Also zeroes all outputs (safe: consumer kernel launches after us).
__global__ __launch_bounds__(128) void chamfer_tile(const float* __restrict__ p1,
                                                    const float* __restrict__ p2,
                                                    float* __restrict__ wsN,
                                                    float* __restrict__ wsM,
                                                    float* __restrict__ out) {
    const int cn = blockIdx.x, cm = blockIdx.y, b = blockIdx.z;
    const int t = threadIdx.x;

    // Distributed zeroing of out[0..3] (loss accum) and out[4..] (smoothed).
    const int bl = (b * CM + cm) * CN + cn;          // [0, 1024)
    if (t < 16) out[4 + bl * 16 + t] = 0.0f;         // 1024*16 = 16384 floats
    if (cn == 0 && cm == 0 && t == 0) out[b] = 0.0f;

    const float* pa = p1 + ((size_t)b * NN + (size_t)cn * TN + t) * 3;
    const float ax = pa[0], ay = pa[1], az = pa[2];
    const float* pb = p2 + ((size_t)b * MM + (size_t)cm * TM + t) * 3;
    const float bx = pb[0], by = pb[1], bz = pb[2];

    const float* __restrict__ oN = p2 + ((size_t)b * MM + (size_t)cm * TM) * 3;  // uniform
    const float* __restrict__ oM = p1 + ((size_t)b * NN + (size_t)cn * TN) * 3;  // uniform

    // Two accumulators per direction to break the fminf dependence chain.
    float mN0 = FLT_BIG, mN1 = FLT_BIG, mM0 = FLT_BIG, mM1 = FLT_BIG;
    #pragma unroll 8
    for (int i = 0; i < TN; i += 2) {
        const float ux0 = oN[3 * i + 0], uy0 = oN[3 * i + 1], uz0 = oN[3 * i + 2];
        const float ux1 = oN[3 * i + 3], uy1 = oN[3 * i + 4], uz1 = oN[3 * i + 5];
        const float vx0 = oM[3 * i + 0], vy0 = oM[3 * i + 1], vz0 = oM[3 * i + 2];
        const float vx1 = oM[3 * i + 3], vy1 = oM[3 * i + 4], vz1 = oM[3 * i + 5];
        float dx, dy, dz;
        dx = ax - ux0; dy = ay - uy0; dz = az - uz0;
        mN0 = fminf(mN0, dx * dx + dy * dy + dz * dz);
        dx = ax - ux1; dy = ay - uy1; dz = az - uz1;
        mN1 = fminf(mN1, dx * dx + dy * dy + dz * dz);
        dx = bx - vx0; dy = by - vy0; dz = bz - vz0;
        mM0 = fminf(mM0, dx * dx + dy * dy + dz * dz);
        dx = bx - vx1; dy = by - vy1; dz = bz - vz1;
        mM1 = fminf(mM1, dx * dx + dy * dy + dz * dz);
    }
    // difference form is exactly >= 0: clamp is a no-op (matches max(d2,0)).
    wsN[((size_t)b * CM + cm) * NN + (size_t)cn * TN + t] = fminf(mN0, mN1);
    wsM[((size_t)b * CN + cn) * MM + (size_t)cm * TM + t] = fminf(mM0, mM1);
}

// K2: min-reduce partials across tiles, sum, atomicAdd into out[b].
// Blocks 0..63 handle the B*NN n-slots; blocks 64..79 the B*MM m-slots.
__global__ __launch_bounds__(256) void chamfer_final(const float* __restrict__ wsN,
                                                     const float* __restrict__ wsM,
                                                     float* __restrict__ out) {
    const int t = threadIdx.x;
    float s;
    int b;
    if (blockIdx.x < 64) {
        const int slot = blockIdx.x * 256 + t;  // [0, B*NN); block spans one b
        b = slot / NN;
        const int n = slot % NN;
        float mn = wsN[(size_t)b * CM * NN + n];
        #pragma unroll
        for (int c = 1; c < CM; ++c)
            mn = fminf(mn, wsN[((size_t)b * CM + c) * NN + n]);
        s = mn;
    } else {
        const int slot = (blockIdx.x - 64) * 256 + t;  // [0, B*MM)
        b = slot / MM;
        const int m = slot % MM;
        float mn = wsM[(size_t)b * CN * MM + m];
        #pragma unroll
        for (int c = 1; c < CN; ++c)
            mn = fminf(mn, wsM[((size_t)b * CN + c) * MM + m]);
        s = mn;
    }
    const float tot = block_reduce_sum_256(s);
    if (t == 0) atomicAdd(&out[b], tot);
}

extern "C" void kernel_launch(void* const* d_in, const int* in_sizes, int n_in,
                              void* d_out, int out_size, void* d_ws, size_t ws_size,
                              hipStream_t stream) {
    const float* p1 = (const float*)d_in[0];  // (B,N,3) fp32
    const float* p2 = (const float*)d_in[1];  // (B,M,3) fp32
    float* out = (float*)d_out;               // [0..3]=total_loss, [4..]=smoothed

    float* wsN = (float*)d_ws;                 // B*CM*NN floats
    float* wsM = wsN + (size_t)BB * CM * NN;   // B*CN*MM floats

    hipLaunchKernelGGL(chamfer_tile, dim3(CN, CM, BB), dim3(TN), 0, stream,
                       p1, p2, wsN, wsM, out);
    hipLaunchKernelGGL(chamfer_final, dim3(64 + 16), dim3(256), 0, stream,
                       wsN, wsM, out);
}

// Round 6
// 15.090 us; speedup vs baseline: 3.7830x; 1.0082x over previous
//
#include <hip/hip_runtime.h>

// Problem constants (B,N,M,D fixed by setup_inputs: 4, 4096, 1024, 3)
#define BB 4
#define NN 4096
#define MM 1024
#define TT 128             // tile edge (both n and m)
#define CN (NN / TT)       // 32 n-tiles
#define CM (MM / TT)       // 8 m-tiles
#define FLT_BIG 3.402823466e38f

// ---------------------------------------------------------------------------
// Math note: the reference's einsum 'bnik,bnjk->bnij' over diffs (B,N,10,3)
// builds a 10x10 Gram matrix of rank <= 3, so ev[...,0] (smallest of 10
// ascending eigenvalues) is exactly 0 => curvature == 0 => smoothed == 0.
// Only the chamfer loss (output 0) carries real values.
//
// Round-4 lesson (measured): in-kernel cross-block handoff needs device-scope
// fences -> per-block L2 writeback on non-coherent XCD L2s -> +45us. Keep the
// reduction as a second kernel (cross-kernel visibility is free).
//
// Workspace (1 MB): wsN[b][cm][n], wsM[b][cn][m] — partial mins, every slot
// written exactly once -> no atomics in pass 1, no init pass.
// ---------------------------------------------------------------------------

// min over one 128-point partner stream (wave-uniform base -> s_load broadcast)
__device__ __forceinline__ float tile_min(const float ax, const float ay, const float az,
                                          const float* __restrict__ o) {
    float m0 = FLT_BIG, m1 = FLT_BIG, m2 = FLT_BIG, m3 = FLT_BIG;
    #pragma unroll 4
    for (int i = 0; i < TT; i += 4) {
        float dx, dy, dz;
        dx = ax - o[3 * i + 0];  dy = ay - o[3 * i + 1];  dz = az - o[3 * i + 2];
        m0 = fminf(m0, dx * dx + dy * dy + dz * dz);
        dx = ax - o[3 * i + 3];  dy = ay - o[3 * i + 4];  dz = az - o[3 * i + 5];
        m1 = fminf(m1, dx * dx + dy * dy + dz * dz);
        dx = ax - o[3 * i + 6];  dy = ay - o[3 * i + 7];  dz = az - o[3 * i + 8];
        m2 = fminf(m2, dx * dx + dy * dy + dz * dz);
        dx = ax - o[3 * i + 9];  dy = ay - o[3 * i + 10]; dz = az - o[3 * i + 11];
        m3 = fminf(m3, dx * dx + dy * dy + dz * dz);
    }
    return fminf(fminf(m0, m1), fminf(m2, m3));  // diff form is exactly >= 0
}

// K1: block (cn,cm,b) covers a 128x128 (n,m) tile with 256 threads.
// Waves 0-1 (t<128): N-direction; waves 2-3: M-direction. Branch is
// wave-uniform, each side reads ONE uniform partner stream.
// Also zeroes all outputs (safe: consumer kernel launches after us).
__global__ __launch_bounds__(256) void chamfer_tile(const float* __restrict__ p1,
                                                    const float* __restrict__ p2,
                                                    float* __restrict__ wsN,
                                                    float* __restrict__ wsM,
                                                    float* __restrict__ out) {
    const int cn = blockIdx.x, cm = blockIdx.y, b = blockIdx.z;
    const int t = threadIdx.x;

    // Distributed zeroing of out[0..3] (loss accum) and out[4..] (smoothed).
    const int bl = (b * CM + cm) * CN + cn;          // [0, 1024)
    if (t < 16) out[4 + bl * 16 + t] = 0.0f;         // 1024*16 = 16384 floats
    if (cn == 0 && cm == 0 && t == 0) out[b] = 0.0f;

    if (t < TT) {
        const float* pa = p1 + ((size_t)b * NN + (size_t)cn * TT + t) * 3;
        const float* __restrict__ o = p2 + ((size_t)b * MM + (size_t)cm * TT) * 3;
        const float mn = tile_min(pa[0], pa[1], pa[2], o);
        wsN[((size_t)b * CM + cm) * NN + (size_t)cn * TT + t] = mn;
    } else {
        const int tm = t - TT;
        const float* pb = p2 + ((size_t)b * MM + (size_t)cm * TT + tm) * 3;
        const float* __restrict__ o = p1 + ((size_t)b * NN + (size_t)cn * TT) * 3;
        const float mn = tile_min(pb[0], pb[1], pb[2], o);
        wsM[((size_t)b * CN + cn) * MM + (size_t)cm * TT + tm] = mn;
    }
}

// K2: min-reduce partials (float4-vectorized), sum, one atomicAdd per block.
// Blocks 0..15: n-slots (each block spans one b: 256 float4 = 1024 n).
// Blocks 16..19: m-slots (block 16+b covers all 1024 m of batch b).
__global__ __launch_bounds__(256) void chamfer_final(const float4* __restrict__ wsN4,
                                                     const float4* __restrict__ wsM4,
                                                     float* __restrict__ out) {
    const int t = threadIdx.x;
    float4 mn;
    int b;
    if (blockIdx.x < 16) {
        const int s = blockIdx.x * 256 + t;   // [0, B*NN/4)
        b = s >> 10;                          // 1024 float4 per batch
        const int n4 = s & 1023;
        mn = wsN4[(size_t)b * CM * (NN / 4) + n4];
        #pragma unroll
        for (int c = 1; c < CM; ++c) {
            const float4 v = wsN4[((size_t)b * CM + c) * (NN / 4) + n4];
            mn.x = fminf(mn.x, v.x); mn.y = fminf(mn.y, v.y);
            mn.z = fminf(mn.z, v.z); mn.w = fminf(mn.w, v.w);
        }
    } else {
        b = blockIdx.x - 16;
        const int m4 = t;                     // 256 float4 per batch
        mn = wsM4[(size_t)b * CN * (MM / 4) + m4];
        #pragma unroll
        for (int c = 1; c < CN; ++c) {
            const float4 v = wsM4[((size_t)b * CN + c) * (MM / 4) + m4];
            mn.x = fminf(mn.x, v.x); mn.y = fminf(mn.y, v.y);
            mn.z = fminf(mn.z, v.z); mn.w = fminf(mn.w, v.w);
        }
    }
    float s = (mn.x + mn.y) + (mn.z + mn.w);

    __shared__ float red[4];
    const int lane = t & 63, wv = t >> 6;
    #pragma unroll
    for (int off = 32; off > 0; off >>= 1) s += __shfl_down(s, off, 64);
    if (lane == 0) red[wv] = s;
    __syncthreads();
    if (t == 0) atomicAdd(&out[b], (red[0] + red[1]) + (red[2] + red[3]));
}

extern "C" void kernel_launch(void* const* d_in, const int* in_sizes, int n_in,
                              void* d_out, int out_size, void* d_ws, size_t ws_size,
                              hipStream_t stream) {
    const float* p1 = (const float*)d_in[0];  // (B,N,3) fp32
    const float* p2 = (const float*)d_in[1];  // (B,M,3) fp32
    float* out = (float*)d_out;               // [0..3]=total_loss, [4..]=smoothed

    float* wsN = (float*)d_ws;                 // B*CM*NN floats (512 KB)
    float* wsM = wsN + (size_t)BB * CM * NN;   // B*CN*MM floats (512 KB)

    hipLaunchKernelGGL(chamfer_tile, dim3(CN, CM, BB), dim3(256), 0, stream,
                       p1, p2, wsN, wsM, out);
    hipLaunchKernelGGL(chamfer_final, dim3(16 + BB), dim3(256), 0, stream,
                       (const float4*)wsN, (const float4*)wsM, out);
}